// Round 1
// baseline (506.324 us; speedup 1.0000x reference)
//
#include <hip/hip_runtime.h>

using u16 = unsigned short;
using u32 = unsigned int;
typedef float f32x4 __attribute__((ext_vector_type(4)));
typedef short s16x8 __attribute__((ext_vector_type(8)));

// ---------- helpers ----------
__device__ __forceinline__ u16 f2bf(float x) {
  u32 u = __float_as_uint(x);
  u += 0x7fffu + ((u >> 16) & 1u);   // RTNE
  return (u16)(u >> 16);
}
__device__ __forceinline__ u32 pack2bf(float lo, float hi) {
  return (u32)f2bf(lo) | ((u32)f2bf(hi) << 16);
}
__device__ __forceinline__ float bf2f(u16 v) {
  return __uint_as_float(((u32)v) << 16);
}
__device__ __forceinline__ void gload16(const u16* g, u16* l) {
  __builtin_amdgcn_global_load_lds(
      (__attribute__((address_space(1))) void*)(u16*)g,
      (__attribute__((address_space(3))) void*)l, 16, 0, 0);
}
__device__ __forceinline__ f32x4 fzero4() {
  f32x4 v = {0.f, 0.f, 0.f, 0.f};
  return v;
}

// ---------- fp32 -> bf16 convert (vectorized) ----------
__global__ __launch_bounds__(256) void k_convert(const float* __restrict__ in,
                                                 u16* __restrict__ out, int n8) {
  int i = blockIdx.x * 256 + threadIdx.x;
  if (i >= n8) return;
  const float4* p = (const float4*)in;
  float4 a = p[2 * i], b = p[2 * i + 1];
  uint4 o;
  o.x = pack2bf(a.x, a.y);
  o.y = pack2bf(a.z, a.w);
  o.z = pack2bf(b.x, b.y);
  o.w = pack2bf(b.z, b.w);
  ((uint4*)out)[i] = o;
}

// ---------- transpose + convert: w [K][N] f32 -> wt [N][K] bf16 ----------
__global__ __launch_bounds__(256) void k_transpose(const float* __restrict__ w,
                                                   u16* __restrict__ wt, int N, int K) {
  __shared__ float tile[64][65];
  int n0 = blockIdx.x * 64, k0 = blockIdx.y * 64;
  int tid = threadIdx.x;
  int rr = tid >> 6, cc = tid & 63;
#pragma unroll
  for (int p = 0; p < 16; ++p)
    tile[p * 4 + rr][cc] = w[(size_t)(k0 + p * 4 + rr) * N + n0 + cc];
  __syncthreads();
#pragma unroll
  for (int p = 0; p < 16; ++p)
    wt[(size_t)(n0 + p * 4 + rr) * K + k0 + cc] = f2bf(tile[cc][p * 4 + rr]);
}

// ---------- GEMM: C[M,N] = A[M,K](bf16) x Bt[N,K](bf16), out bf16 or fp32 ----------
template <bool OBF>
__global__ __launch_bounds__(256) void k_gemm_bt(const u16* __restrict__ A,
                                                 const u16* __restrict__ Bt,
                                                 void* __restrict__ Out, int Nd, int Kd) {
  __shared__ u16 As[2][128 * 32];
  __shared__ u16 Bs[2][128 * 32];
  u32 bid = blockIdx.x, nwg = gridDim.x;
  u32 wgid = (bid & 7) * (nwg >> 3) + (bid >> 3);   // XCD swizzle (nwg % 8 == 0)
  int ntn = Nd >> 7;
  int bm = wgid / ntn, bn = wgid % ntn;
  int tid = threadIdx.x, w = tid >> 6, lane = tid & 63;
  int wm = w >> 1, wn = w & 1;
  int lg = lane >> 4, lq = lane & 15;

  const u16* a0 = A + (size_t)(bm * 128 + w * 32 + (lane >> 2)) * Kd + (lane & 3) * 8;
  const u16* a1 = a0 + (size_t)16 * Kd;
  const u16* b0 = Bt + (size_t)(bn * 128 + w * 32 + (lane >> 2)) * Kd + (lane & 3) * 8;
  const u16* b1 = b0 + (size_t)16 * Kd;

  auto stage = [&](int buf, int k0) {
    gload16(a0 + k0, &As[buf][w * 1024]);
    gload16(a1 + k0, &As[buf][w * 1024 + 512]);
    gload16(b0 + k0, &Bs[buf][w * 1024]);
    gload16(b1 + k0, &Bs[buf][w * 1024 + 512]);
  };

  f32x4 acc[4][4];
#pragma unroll
  for (int m = 0; m < 4; ++m)
#pragma unroll
    for (int n = 0; n < 4; ++n) acc[m][n] = fzero4();

  int nk = Kd >> 5;
  stage(0, 0);
  __syncthreads();
  for (int t = 0; t < nk; ++t) {
    int cur = t & 1;
    if (t + 1 < nk) stage(cur ^ 1, (t + 1) << 5);
    s16x8 af[4], bfr[4];
#pragma unroll
    for (int m = 0; m < 4; ++m)
      af[m] = *(const s16x8*)&As[cur][(wm * 64 + m * 16 + lq) * 32 + lg * 8];
#pragma unroll
    for (int n = 0; n < 4; ++n)
      bfr[n] = *(const s16x8*)&Bs[cur][(wn * 64 + n * 16 + lq) * 32 + lg * 8];
#pragma unroll
    for (int m = 0; m < 4; ++m)
#pragma unroll
      for (int n = 0; n < 4; ++n)
        acc[m][n] = __builtin_amdgcn_mfma_f32_16x16x32_bf16(af[m], bfr[n], acc[m][n], 0, 0, 0);
    __syncthreads();
  }

  int r0 = bm * 128 + wm * 64, c0 = bn * 128 + wn * 64;
  if (OBF) {
    u16* O = (u16*)Out;
#pragma unroll
    for (int m = 0; m < 4; ++m)
#pragma unroll
      for (int n = 0; n < 4; ++n)
#pragma unroll
        for (int r = 0; r < 4; ++r)
          O[(size_t)(r0 + m * 16 + lg * 4 + r) * Nd + c0 + n * 16 + lq] = f2bf(acc[m][n][r]);
  } else {
    float* O = (float*)Out;
#pragma unroll
    for (int m = 0; m < 4; ++m)
#pragma unroll
      for (int n = 0; n < 4; ++n)
#pragma unroll
        for (int r = 0; r < 4; ++r)
          O[(size_t)(r0 + m * 16 + lg * 4 + r) * Nd + c0 + n * 16 + lq] = acc[m][n][r];
  }
}

// ---------- RoPE + scatter to Q / K / V^T ----------
__device__ __forceinline__ u32 rope_pair(short a, short b, float c, float s) {
  float x0 = bf2f((u16)a), x1 = bf2f((u16)b);
  return pack2bf(x0 * c - x1 * s, x0 * s + x1 * c);
}

__global__ __launch_bounds__(256) void k_rope_scatter(const u16* __restrict__ qkv,
                                                      const float* __restrict__ fr,
                                                      u16* __restrict__ Q, u16* __restrict__ K,
                                                      u16* __restrict__ Vt) {
  int idx = blockIdx.x * 256 + threadIdx.x;
  if (idx >= 8192 * 384) return;
  int row = idx / 384, g = idx % 384;
  int b = row >> 11, t = row & 2047;
  int col = g * 8;
  const u16* src = qkv + (size_t)row * 3072 + col;
  if (col < 2560) {
    int isq = col < 2048;
    int c2 = isq ? col : col - 2048;
    int h = c2 >> 7, d = c2 & 127;
    u16* dst = isq ? (Q + ((size_t)(b * 16 + h) * 2048 + t) * 128 + d)
                   : (K + ((size_t)(b * 4 + h) * 2048 + t) * 128 + d);
    const float4* fp = (const float4*)(fr + (size_t)t * 128 + d);
    float4 f01 = fp[0], f23 = fp[1];
    s16x8 v = *(const s16x8*)src;
    uint4 o;
    o.x = rope_pair(v[0], v[1], f01.x, f01.y);
    o.y = rope_pair(v[2], v[3], f01.z, f01.w);
    o.z = rope_pair(v[4], v[5], f23.x, f23.y);
    o.w = rope_pair(v[6], v[7], f23.z, f23.w);
    *(uint4*)dst = o;
  } else {
    int c2 = col - 2560;
    int h = c2 >> 7, d = c2 & 127;
    s16x8 v = *(const s16x8*)src;
    u16* base = Vt + ((size_t)(b * 4 + h) * 128 + d) * 2048 + t;
#pragma unroll
    for (int j = 0; j < 8; ++j) base[(size_t)j * 2048] = (u16)v[j];
  }
}

// ---------- flash attention (non-causal, GQA) ----------
// Q [64bh][2048][128], K [16bkv][2048][128], Vt [16bkv][128][2048] -> Y [B*T][2048] bf16
__global__ __launch_bounds__(256) void k_attn(const u16* __restrict__ Qg,
                                              const u16* __restrict__ Kg,
                                              const u16* __restrict__ Vg,
                                              u16* __restrict__ Yg) {
  __shared__ u16 Kl[64 * 128];
  __shared__ u16 Vl[128 * 64];
  __shared__ u16 Pl[4 * 1088];   // per-wave 8 x (136) u16, padded
  u32 bid = blockIdx.x;
  u32 wgid = (bid & 7) * 256 + (bid >> 3);   // XCD swizzle (2048 wgs)
  int qt = wgid & 31, bh = wgid >> 5;
  int b = bh >> 4, h = bh & 15, kvh = h >> 2;
  int tid = threadIdx.x, w = tid >> 6, lane = tid & 63;
  int lg = lane >> 4, lq = lane & 15;
  const u16* Qb = Qg + ((size_t)bh * 2048 + qt * 64 + w * 16) * 128;
  const u16* Kb = Kg + (size_t)(b * 4 + kvh) * 2048 * 128;
  const u16* Vb = Vg + (size_t)(b * 4 + kvh) * 128 * 2048;

  s16x8 qf[4];
#pragma unroll
  for (int kc = 0; kc < 4; ++kc)
    qf[kc] = *(const s16x8*)(Qb + lq * 128 + kc * 32 + lg * 8);

  f32x4 o[8];
#pragma unroll
  for (int i = 0; i < 8; ++i) o[i] = fzero4();
  float m_run = -3.0e38f, l_run = 0.f;
  const float SCL = 0.08838834764831845f * 1.44269504088896341f;  // 1/sqrt(128)*log2(e)

  int krow = w * 16 + lg;
  int vrow = w * 32 + (lane >> 3);
  int kch = lq, vch = lane & 7;

  for (int kt = 0; kt < 32; ++kt) {
    int key0 = kt * 64;
    __syncthreads();
#pragma unroll
    for (int i = 0; i < 4; ++i) {
      int r = krow + i * 4;
      gload16(Kb + (size_t)(key0 + r) * 128 + ((kch ^ (r & 7)) * 8), &Kl[(w * 16 + i * 4) * 128]);
    }
#pragma unroll
    for (int i = 0; i < 4; ++i) {
      int d = vrow + i * 8;
      gload16(Vb + (size_t)d * 2048 + key0 + ((vch ^ (d & 7)) * 8), &Vl[(w * 32 + i * 8) * 64]);
    }
    __syncthreads();

    // S^T = K x Q^T  (keys in M, q-rows in N)
    f32x4 s[4];
#pragma unroll
    for (int kf = 0; kf < 4; ++kf) {
      s[kf] = fzero4();
#pragma unroll
      for (int kc = 0; kc < 4; ++kc) {
        s16x8 a = *(const s16x8*)&Kl[(kf * 16 + lq) * 128 + (((kc * 4 + lg) ^ (lq & 7)) * 8)];
        s[kf] = __builtin_amdgcn_mfma_f32_16x16x32_bf16(a, qf[kc], s[kf], 0, 0, 0);
      }
    }

    // online softmax (stats lane-local per q-column, replicated across 4 lane-groups)
    float sv[16];
    float mt = -3.0e38f;
#pragma unroll
    for (int kf = 0; kf < 4; ++kf)
#pragma unroll
      for (int r = 0; r < 4; ++r) {
        float x = s[kf][r] * SCL;
        sv[kf * 4 + r] = x;
        mt = fmaxf(mt, x);
      }
    mt = fmaxf(mt, __shfl_xor(mt, 16));
    mt = fmaxf(mt, __shfl_xor(mt, 32));
    float mnew = fmaxf(m_run, mt);
    float alpha = exp2f(m_run - mnew);
    m_run = mnew;
    float p[16];
    float ps = 0.f;
#pragma unroll
    for (int j = 0; j < 16; ++j) {
      p[j] = exp2f(sv[j] - mnew);
      ps += p[j];
    }
    ps += __shfl_xor(ps, 16);
    ps += __shfl_xor(ps, 32);
    l_run = l_run * alpha + ps;
#pragma unroll
    for (int i = 0; i < 8; ++i) o[i] *= alpha;

    // write P^T to LDS in PV B-fragment layout: [kg=key/8][q][8], padded stride 136
#pragma unroll
    for (int kf = 0; kf < 4; ++kf) {
      uint2 val;
      val.x = pack2bf(p[kf * 4 + 0], p[kf * 4 + 1]);
      val.y = pack2bf(p[kf * 4 + 2], p[kf * 4 + 3]);
      int kg = 2 * kf + (lg >> 1);
      *(uint2*)&Pl[w * 1088 + kg * 136 + lq * 8 + (lg & 1) * 4] = val;
    }
    asm volatile("s_waitcnt lgkmcnt(0)" ::: "memory");
    __builtin_amdgcn_sched_barrier(0);

    // O^T += V^T x P^T
#pragma unroll
    for (int c = 0; c < 2; ++c) {
      s16x8 pf = *(const s16x8*)&Pl[w * 1088 + (c * 4 + lg) * 136 + lq * 8];
#pragma unroll
      for (int df = 0; df < 8; ++df) {
        int dr = df * 16 + lq;
        s16x8 vf = *(const s16x8*)&Vl[dr * 64 + (((c * 4 + lg) ^ (lq & 7)) * 8)];
        o[df] = __builtin_amdgcn_mfma_f32_16x16x32_bf16(vf, pf, o[df], 0, 0, 0);
      }
    }
  }

  float inv = 1.0f / l_run;
  int qrow = qt * 64 + w * 16 + lq;
  u16* yr = Yg + ((size_t)(b * 2048 + qrow)) * 2048 + h * 128 + lg * 4;
#pragma unroll
  for (int df = 0; df < 8; ++df) {
    uint2 val;
    val.x = pack2bf(o[df][0] * inv, o[df][1] * inv);
    val.y = pack2bf(o[df][2] * inv, o[df][3] * inv);
    *(uint2*)&yr[df * 16] = val;
  }
}

// ---------- launch ----------
extern "C" void kernel_launch(void* const* d_in, const int* in_sizes, int n_in,
                              void* d_out, int out_size, void* d_ws, size_t ws_size,
                              hipStream_t stream) {
  const float* x = (const float*)d_in[0];
  const float* fr = (const float*)d_in[1];
  const float* wqkv = (const float*)d_in[2];
  const float* wproj = (const float*)d_in[3];
  char* ws = (char*)d_ws;
  u16* xbf = (u16*)(ws + 0);                  // 33.5 MB (reused as y after GEMM1)
  u16* wqkvT = (u16*)(ws + 33554432);         // 12.6 MB
  u16* wprojT = (u16*)(ws + 46137344);        // 8.4 MB
  u16* qkv = (u16*)(ws + 54525952);           // 50.3 MB
  u16* Qb = (u16*)(ws + 104857600);           // 33.5 MB
  u16* Kb = (u16*)(ws + 138412032);           // 8.4 MB
  u16* Vtb = (u16*)(ws + 146800640);          // 8.4 MB  (end: 155.2 MB)

  k_convert<<<8192, 256, 0, stream>>>(x, xbf, 8192 * 2048 / 8);
  k_transpose<<<dim3(48, 32), 256, 0, stream>>>(wqkv, wqkvT, 3072, 2048);
  k_transpose<<<dim3(32, 32), 256, 0, stream>>>(wproj, wprojT, 2048, 2048);
  k_gemm_bt<true><<<64 * 24, 256, 0, stream>>>(xbf, wqkvT, qkv, 3072, 2048);
  k_rope_scatter<<<12288, 256, 0, stream>>>(qkv, fr, Qb, Kb, Vtb);
  k_attn<<<2048, 256, 0, stream>>>(Qb, Kb, Vtb, xbf);
  k_gemm_bt<false><<<64 * 16, 256, 0, stream>>>(xbf, wprojT, d_out, 2048, 2048);
}